// Round 2
// baseline (2040.485 us; speedup 1.0000x reference)
//
#include <hip/hip_runtime.h>
#include <hip/hip_bf16.h>
#include <cstdint>
#include <cstddef>

// ---- problem constants ----
#define B_   2
#define D_   8
#define C_   256
#define W_   84
#define H_   84
#define NH   8
#define HD   32
#define NW1  576          // windows per batch (4*12*12)
#define NWIN 1152         // total windows
#define NTOK 98           // tokens per window (2*7*7)
#define MROWS (NWIN*NTOK) // 112896 rows
#define MUNIT 6272        // lcm(98,128): chunk unit (64 windows)

typedef __attribute__((ext_vector_type(8))) short sh8;
typedef __attribute__((ext_vector_type(4))) float f32x4;
typedef __hip_bfloat16 bf16;

// ---------------- fp32 -> bf16 weight convert ----------------
__global__ __launch_bounds__(256) void k_f2b(const float* __restrict__ in,
                                             bf16* __restrict__ out, int n) {
  int i = blockIdx.x * 256 + threadIdx.x;
  if (i < n) out[i] = __float2bfloat16(in[i]);
}

// map GLOBAL windowed row r -> original (b, d0, h0, w0)
__device__ __forceinline__ void row_to_src(int r, int& b, int& d0, int& h0, int& w0) {
  int win = r / NTOK, n = r - win * NTOK;
  b = win / NW1;
  int widx = win - b * NW1;
  int id = widx / 144; int rem = widx - id * 144; int ih = rem / 12, iw = rem - ih * 12;
  int jd = n / 49; int nr = n - jd * 49; int jh = nr / 7, jw = nr - jh * 7;
  int sd = id * 2 + jd, sh = ih * 7 + jh, sw = iw * 7 + jw;
  d0 = (sd + 1) & 7;
  h0 = sh + 3; if (h0 >= 84) h0 -= 84;
  w0 = sw + 3; if (w0 >= 84) w0 -= 84;
}

// ---------------- LN1 + shift + window partition (chunk-local out) ----------------
__global__ __launch_bounds__(256) void k_ln1_window(
    const float* __restrict__ x, const float* __restrict__ g,
    const float* __restrict__ bb, bf16* __restrict__ xw, int r0) {
  int rl = blockIdx.x, c = threadIdx.x;
  int b, d0, h0, w0; row_to_src(r0 + rl, b, d0, h0, w0);
  float v = x[((((size_t)b * D_ + d0) * C_ + c) * W_ + w0) * H_ + h0];
  float s = v, s2 = v * v;
#pragma unroll
  for (int off = 32; off; off >>= 1) { s += __shfl_down(s, off, 64); s2 += __shfl_down(s2, off, 64); }
  __shared__ float red[8];
  int lane = c & 63, wv = c >> 6;
  if (lane == 0) { red[wv] = s; red[4 + wv] = s2; }
  __syncthreads();
  float ts = red[0] + red[1] + red[2] + red[3];
  float ts2 = red[4] + red[5] + red[6] + red[7];
  float mu = ts * (1.f / 256.f);
  float var = ts2 * (1.f / 256.f) - mu * mu;
  float rs = rsqrtf(var + 1e-5f);
  xw[(size_t)rl * C_ + c] = __float2bfloat16((v - mu) * rs * g[c] + bb[c]);
}

// ---------------- bf16 B^T GEMM: out = A(MxK) @ Bw(NxK)^T ----------------
// EPI 0: (+bias) -> bf16    EPI 1: +bias, GELU -> bf16
// EPI 2: +bias +res, scatter f32 to (B,D,C,W,H) d_out (rows are chunk-local; r0 = global offset)
template <int EPI>
__global__ __launch_bounds__(256) void k_gemm_bt(
    const bf16* __restrict__ A, const bf16* __restrict__ Bw,
    int M, int N, int K,
    const float* __restrict__ bias, const float* __restrict__ res,
    void* __restrict__ outv, int r0) {
  __shared__ __align__(16) short sA[128 * 64];
  __shared__ __align__(16) short sB[128 * 64];
  int nbn = N >> 7;
  int bm = blockIdx.x / nbn, bn = blockIdx.x - bm * nbn;
  int tid = threadIdx.x;
  int lane = tid & 63, wv = tid >> 6;
  int wr = wv >> 1, wc = wv & 1;
  f32x4 acc[4][4] = {};
  const short* Ag = (const short*)A + (size_t)bm * 128 * K;
  const short* Bg = (const short*)Bw + (size_t)bn * 128 * K;
  int o = tid << 3;
  int srow = o >> 6, scol = o & 63;
  int nk = K >> 6;
  for (int kt = 0; kt < nk; ++kt) {
    const short* ga = Ag + (size_t)srow * K + kt * 64 + scol;
    const short* gb = Bg + (size_t)srow * K + kt * 64 + scol;
#pragma unroll
    for (int rr = 0; rr < 4; ++rr) {
      *(sh8*)&sA[o + rr * 2048] = *(const sh8*)(ga + (size_t)(rr * 32) * K);
      *(sh8*)&sB[o + rr * 2048] = *(const sh8*)(gb + (size_t)(rr * 32) * K);
    }
    __syncthreads();
#pragma unroll
    for (int ks = 0; ks < 2; ++ks) {
      sh8 af[4], bfr[4];
      int rb = wr * 64 + (lane & 15);
      int cb = wc * 64 + (lane & 15);
      int kof = ks * 32 + (lane >> 4) * 8;
#pragma unroll
      for (int m = 0; m < 4; ++m) af[m] = *(const sh8*)&sA[(rb + m * 16) * 64 + kof];
#pragma unroll
      for (int n2 = 0; n2 < 4; ++n2) bfr[n2] = *(const sh8*)&sB[(cb + n2 * 16) * 64 + kof];
#pragma unroll
      for (int m = 0; m < 4; ++m)
#pragma unroll
        for (int n2 = 0; n2 < 4; ++n2)
          acc[m][n2] = __builtin_amdgcn_mfma_f32_16x16x32_bf16(af[m], bfr[n2], acc[m][n2], 0, 0, 0);
    }
    __syncthreads();
  }
  // epilogue: C/D layout col=lane&15, row=(lane>>4)*4+j
  int rbase = bm * 128 + wr * 64 + ((lane >> 4) << 2);
  int cbase = bn * 128 + wc * 64 + (lane & 15);
#pragma unroll
  for (int m = 0; m < 4; ++m) {
#pragma unroll
    for (int j = 0; j < 4; ++j) {
      int r = rbase + m * 16 + j;
      if (EPI == 2) {
        int b, d0, h0, w0; row_to_src(r0 + r, b, d0, h0, w0);
        size_t obase = (((size_t)b * D_ + d0) * C_) * (W_ * H_) + w0 * H_ + h0;
#pragma unroll
        for (int n2 = 0; n2 < 4; ++n2) {
          int cc = cbase + n2 * 16;
          float v = acc[m][n2][j] + bias[cc] + res[(size_t)r * N + cc];
          ((float*)outv)[obase + (size_t)cc * (W_ * H_)] = v;
        }
      } else {
#pragma unroll
        for (int n2 = 0; n2 < 4; ++n2) {
          int cc = cbase + n2 * 16;
          float v = acc[m][n2][j];
          if (bias) v += bias[cc];
          if (EPI == 1) v = 0.5f * v * (1.f + erff(v * 0.70710678118f));
          ((bf16*)outv)[(size_t)r * N + cc] = __float2bfloat16(v);
        }
      }
    }
  }
}

// ---------------- windowed attention (chunk-local qkv/aout) ----------------
__global__ __launch_bounds__(128) void k_attn(
    const bf16* __restrict__ qkv, const float* __restrict__ rpb,
    bf16* __restrict__ aout, int win0) {
  int blk = blockIdx.x;
  int wl = blk >> 3, h = blk & 7;
  int wg = win0 + wl;                 // global window index
  int widx = wg % NW1;
  int id = widx / 144; int rem = widx - id * 144; int ih = rem / 12, iw = rem - ih * 12;
  int tid = threadIdx.x;
  __shared__ __align__(16) float kk[NTOK][HD];
  __shared__ __align__(16) float vv[NTOK][HD];
  __shared__ int binf[NTOK];
  __shared__ int cinf[NTOK];
  const size_t base = (size_t)wl * NTOK * 768;
  for (int idx = tid; idx < NTOK * HD; idx += 128) {
    int row = idx >> 5, d = idx & 31;
    size_t rb = base + (size_t)row * 768 + h * 32 + d;
    kk[row][d] = __bfloat162float(qkv[rb + 256]);
    vv[row][d] = __bfloat162float(qkv[rb + 512]);
  }
  if (tid < NTOK) {
    int jd = tid / 49; int nr = tid - jd * 49; int jh = nr / 7, jw = nr - jh * 7;
    binf[tid] = jd * 169 + jh * 13 + jw;  // rel-pos base: idx = bi - bj + 253
    int sd = id * 2 + jd, sh = ih * 7 + jh, sw = iw * 7 + jw;
    int dg = (sd < 6) ? 0 : ((sd < 7) ? 1 : 2);
    int hg = (sh < 77) ? 0 : ((sh < 81) ? 1 : 2);
    int wgr = (sw < 77) ? 0 : ((sw < 81) ? 1 : 2);
    cinf[tid] = dg * 9 + hg * 3 + wgr;    // shift-mask region code
  }
  __syncthreads();
  if (tid >= NTOK) return;
  float q[HD];
  size_t qb = base + (size_t)tid * 768 + h * 32;
#pragma unroll
  for (int d = 0; d < HD; ++d) q[d] = __bfloat162float(qkv[qb + d]) * 0.17677669529663687f;
  int bi = binf[tid], ci = cinf[tid];
  float acc[HD] = {};
  float l = 0.f;
  for (int j = 0; j < NTOK; ++j) {
    float s = 0.f;
#pragma unroll
    for (int d = 0; d < HD; ++d) s += q[d] * kk[j][d];
    s += rpb[(bi - binf[j] + 253) * 8 + h];
    if (ci != cinf[j]) s -= 100.f;   // additive shift mask
    float p = __expf(s);             // scores O(1): unnormalized softmax is safe
    l += p;
#pragma unroll
    for (int d = 0; d < HD; ++d) acc[d] += p * vv[j][d];
  }
  float inv = 1.f / l;
  size_t ob = ((size_t)wl * NTOK + tid) * C_ + h * 32;
#pragma unroll
  for (int d = 0; d < HD; ++d) aout[ob + d] = __float2bfloat16(acc[d] * inv);
}

// ---------------- residual (gather x) + LN2 (chunk-local) ----------------
__global__ __launch_bounds__(256) void k_xres_ln2(
    const float* __restrict__ x, const bf16* __restrict__ pout,
    const float* __restrict__ g, const float* __restrict__ bb,
    float* __restrict__ xres, bf16* __restrict__ ln2, int r0) {
  int rl = blockIdx.x, c = threadIdx.x;
  int b, d0, h0, w0; row_to_src(r0 + rl, b, d0, h0, w0);
  float xr = x[((((size_t)b * D_ + d0) * C_ + c) * W_ + w0) * H_ + h0]
           + __bfloat162float(pout[(size_t)rl * C_ + c]);
  xres[(size_t)rl * C_ + c] = xr;
  float s = xr, s2 = xr * xr;
#pragma unroll
  for (int off = 32; off; off >>= 1) { s += __shfl_down(s, off, 64); s2 += __shfl_down(s2, off, 64); }
  __shared__ float red[8];
  int lane = c & 63, wv = c >> 6;
  if (lane == 0) { red[wv] = s; red[4 + wv] = s2; }
  __syncthreads();
  float ts = red[0] + red[1] + red[2] + red[3];
  float ts2 = red[4] + red[5] + red[6] + red[7];
  float mu = ts * (1.f / 256.f);
  float var = ts2 * (1.f / 256.f) - mu * mu;
  float rs = rsqrtf(var + 1e-5f);
  ln2[(size_t)rl * C_ + c] = __float2bfloat16((xr - mu) * rs * g[c] + bb[c]);
}

// ---------------- launch ----------------
extern "C" void kernel_launch(void* const* d_in, const int* in_sizes, int n_in,
                              void* d_out, int out_size, void* d_ws, size_t ws_size,
                              hipStream_t stream) {
  const float* x      = (const float*)d_in[0];
  const float* n1g    = (const float*)d_in[1];
  const float* n1b    = (const float*)d_in[2];
  const float* qkv_w  = (const float*)d_in[3];
  const float* rpb    = (const float*)d_in[4];
  const float* proj_w = (const float*)d_in[5];
  const float* proj_b = (const float*)d_in[6];
  const float* n2g    = (const float*)d_in[7];
  const float* n2b    = (const float*)d_in[8];
  const float* fc1_w  = (const float*)d_in[9];
  const float* fc1_b  = (const float*)d_in[10];
  const float* fc2_w  = (const float*)d_in[11];
  const float* fc2_b  = (const float*)d_in[12];
  float* out = (float*)d_out;

  // ---- weights (persistent) ----
  char* w = (char*)d_ws;
  size_t off = 0;
  bf16* wq = (bf16*)(w + off); off += (size_t)768 * 256 * 2;
  bf16* wp = (bf16*)(w + off); off += (size_t)256 * 256 * 2;
  bf16* w1 = (bf16*)(w + off); off += (size_t)1024 * 256 * 2;
  bf16* w2 = (bf16*)(w + off); off += (size_t)1024 * 256 * 2;
  size_t wbytes = off;

  // ---- adaptive chunking: largest divisor of 18 units that fits ws_size ----
  // per-chunk bytes = Mc * (512 xw + 1536 qkv + 1024 xres + 2048 hid) = Mc*5120
  const int divs[6] = {18, 9, 6, 3, 2, 1};
  int ku = 1;
  for (int i = 0; i < 6; ++i) {
    if (wbytes + (size_t)divs[i] * MUNIT * 5120 + 1024 <= ws_size) { ku = divs[i]; break; }
  }
  const int Mc = ku * MUNIT;        // chunk rows (multiple of 128 and 98)
  const int nch = 18 / ku;
  const int nwc = Mc / NTOK;        // windows per chunk

  bf16*  xw   = (bf16*)(w + off);            off += (size_t)Mc * 512;
  char*  qreg = w + off;                     off += (size_t)Mc * 1536;
  float* xres = (float*)(w + off);           off += (size_t)Mc * 1024;
  bf16*  hid  = (bf16*)(w + off);
  bf16* qkvb = (bf16*)qreg;
  bf16* aout = xw;                                    // alias: xw dead after qkv GEMM
  bf16* pout = (bf16*)qreg;                           // alias: qkv dead after attn
  bf16* ln2b = (bf16*)(qreg + (size_t)Mc * 512);      // alongside pout in qkv region

  // weights -> bf16 (once per call)
  k_f2b<<<(196608 + 255) / 256, 256, 0, stream>>>(qkv_w, wq, 196608);
  k_f2b<<<(65536 + 255) / 256, 256, 0, stream>>>(proj_w, wp, 65536);
  k_f2b<<<(262144 + 255) / 256, 256, 0, stream>>>(fc1_w, w1, 262144);
  k_f2b<<<(262144 + 255) / 256, 256, 0, stream>>>(fc2_w, w2, 262144);

  for (int ch = 0; ch < nch; ++ch) {
    int r0 = ch * Mc;
    int win0 = ch * nwc;
    // LN1 + shift + window
    k_ln1_window<<<Mc, 256, 0, stream>>>(x, n1g, n1b, xw, r0);
    // qkv GEMM
    k_gemm_bt<0><<<(Mc / 128) * 6, 256, 0, stream>>>(
        xw, wq, Mc, 768, 256, nullptr, nullptr, qkvb, 0);
    // attention
    k_attn<<<nwc * NH, 128, 0, stream>>>(qkvb, rpb, aout, win0);
    // proj GEMM (+bias)
    k_gemm_bt<0><<<(Mc / 128) * 2, 256, 0, stream>>>(
        aout, wp, Mc, 256, 256, proj_b, nullptr, pout, 0);
    // residual + LN2
    k_xres_ln2<<<Mc, 256, 0, stream>>>(x, pout, n2g, n2b, xres, ln2b, r0);
    // fc1 (+bias, GELU)
    k_gemm_bt<1><<<(Mc / 128) * 8, 256, 0, stream>>>(
        ln2b, w1, Mc, 1024, 256, fc1_b, nullptr, hid, 0);
    // fc2 (+bias, +residual) -> scatter f32 directly to (B,D,C,W,H) out
    k_gemm_bt<2><<<(Mc / 128) * 2, 256, 0, stream>>>(
        hid, w2, Mc, 256, 1024, fc2_b, xres, out, r0);
  }
}

// Round 3
// 1976.721 us; speedup vs baseline: 1.0323x; 1.0323x over previous
//
#include <hip/hip_runtime.h>
#include <hip/hip_bf16.h>
#include <cstdint>
#include <cstddef>

// ---- problem constants ----
#define B_   2
#define D_   8
#define C_   256
#define W_   84
#define H_   84
#define NH   8
#define HD   32
#define NW1  576          // windows per batch (4*12*12)
#define NWIN 1152         // total windows
#define NTOK 98           // tokens per window (2*7*7)
#define MROWS (NWIN*NTOK) // 112896 rows
#define MUNIT 6272        // lcm(98,128): chunk unit (64 windows)
#define WH   7056         // W_*H_

typedef __attribute__((ext_vector_type(8))) short sh8;
typedef __attribute__((ext_vector_type(4))) float f32x4;
typedef __hip_bfloat16 bf16;

// ---------------- fp32 -> bf16 weight convert ----------------
__global__ __launch_bounds__(256) void k_f2b(const float* __restrict__ in,
                                             bf16* __restrict__ out, int n) {
  int i = blockIdx.x * 256 + threadIdx.x;
  if (i < n) out[i] = __float2bfloat16(in[i]);
}

// map GLOBAL windowed row r -> original (b, d0, h0, w0)
__device__ __forceinline__ void row_to_src(int r, int& b, int& d0, int& h0, int& w0) {
  int win = r / NTOK, n = r - win * NTOK;
  b = win / NW1;
  int widx = win - b * NW1;
  int id = widx / 144; int rem = widx - id * 144; int ih = rem / 12, iw = rem - ih * 12;
  int jd = n / 49; int nr = n - jd * 49; int jh = nr / 7, jw = nr - jh * 7;
  int sd = id * 2 + jd, sh = ih * 7 + jh, sw = iw * 7 + jw;
  d0 = (sd + 1) & 7;
  h0 = sh + 3; if (h0 >= 84) h0 -= 84;
  w0 = sw + 3; if (w0 >= 84) w0 -= 84;
}

// ---------------- x (B,D,C,W,H) -> xt rows (b,d,w,h) x C, both sides coalesced ----------------
__global__ __launch_bounds__(256) void k_xpose(const float* __restrict__ x,
                                               float* __restrict__ xt) {
  int blk = blockIdx.x;          // (bd, w0, ch)
  int ch = blk & 1;
  int t = blk >> 1;
  int w0 = t % 84;
  int bd = t / 84;               // b*8+d0
  __shared__ float tile[128][85];  // stride 85: gcd(85,32)=1 -> conflict-free col reads
  int tid = threadIdx.x;
  const float* src = x + ((size_t)bd * 256 + ch * 128) * WH + w0 * 84;
  for (int idx = tid; idx < 128 * 21; idx += 256) {
    int c = idx / 21, h4 = idx - c * 21;
    float4 v = *(const float4*)(src + (size_t)c * WH + h4 * 4);
    tile[c][h4 * 4 + 0] = v.x; tile[c][h4 * 4 + 1] = v.y;
    tile[c][h4 * 4 + 2] = v.z; tile[c][h4 * 4 + 3] = v.w;
  }
  __syncthreads();
  float* dst = xt + ((size_t)bd * 84 + w0) * 84 * 256 + ch * 128;
  for (int idx = tid; idx < 84 * 128; idx += 256) {
    int h = idx >> 7, c = idx & 127;
    dst[(size_t)h * 256 + c] = tile[c][h];
  }
}

// ---------------- LN1 (+shift/window gather): wave per row, float4 ----------------
template <bool XT>
__global__ __launch_bounds__(256) void k_ln1v(
    const float* __restrict__ xin, const float* __restrict__ g,
    const float* __restrict__ bb, bf16* __restrict__ xw, int r0) {
  int rl = blockIdx.x * 4 + (threadIdx.x >> 6);
  int lane = threadIdx.x & 63;
  int b, d0, h0, w0; row_to_src(r0 + rl, b, d0, h0, w0);
  int c0 = lane * 4;
  float4 v;
  if (XT) {
    v = *(const float4*)(xin + (((size_t)(b * 8 + d0) * 84 + w0) * 84 + h0) * 256 + c0);
  } else {
    const float* p = xin + ((size_t)(b * 8 + d0) * 256 + c0) * WH + w0 * 84 + h0;
    v.x = p[0]; v.y = p[WH]; v.z = p[2 * WH]; v.w = p[3 * WH];
  }
  float s = v.x + v.y + v.z + v.w;
  float s2 = v.x * v.x + v.y * v.y + v.z * v.z + v.w * v.w;
#pragma unroll
  for (int off = 32; off; off >>= 1) { s += __shfl_xor(s, off, 64); s2 += __shfl_xor(s2, off, 64); }
  float mu = s * (1.f / 256.f);
  float var = s2 * (1.f / 256.f) - mu * mu;
  float rs = rsqrtf(var + 1e-5f);
  float4 gg = *(const float4*)(g + c0);
  float4 bv = *(const float4*)(bb + c0);
  bf16 tmp[4];
  tmp[0] = __float2bfloat16((v.x - mu) * rs * gg.x + bv.x);
  tmp[1] = __float2bfloat16((v.y - mu) * rs * gg.y + bv.y);
  tmp[2] = __float2bfloat16((v.z - mu) * rs * gg.z + bv.z);
  tmp[3] = __float2bfloat16((v.w - mu) * rs * gg.w + bv.w);
  *(ushort4*)(&xw[(size_t)rl * 256 + c0]) = *(ushort4*)tmp;
}

// ---------------- bf16 B^T GEMM: out = A(MxK) @ Bw(NxK)^T ----------------
// EPI 0: (+bias) -> bf16    EPI 1: +bias, GELU -> bf16
// EPI 2: +bias +res -> f32 linear    EPI 3: +bias +res -> f32 scatter to (B,D,C,W,H)
template <int EPI>
__global__ __launch_bounds__(256) void k_gemm_bt(
    const bf16* __restrict__ A, const bf16* __restrict__ Bw,
    int M, int N, int K,
    const float* __restrict__ bias, const float* __restrict__ res,
    void* __restrict__ outv, int r0) {
  __shared__ __align__(16) short sA[128 * 64];
  __shared__ __align__(16) short sB[128 * 64];
  int nbn = N >> 7;
  int bm = blockIdx.x / nbn, bn = blockIdx.x - bm * nbn;
  int tid = threadIdx.x;
  int lane = tid & 63, wv = tid >> 6;
  int wr = wv >> 1, wc = wv & 1;
  f32x4 acc[4][4] = {};
  const short* Ag = (const short*)A + (size_t)bm * 128 * K;
  const short* Bg = (const short*)Bw + (size_t)bn * 128 * K;
  int o = tid << 3;
  int srow = o >> 6, scol = o & 63;
  int nk = K >> 6;
  for (int kt = 0; kt < nk; ++kt) {
    const short* ga = Ag + (size_t)srow * K + kt * 64 + scol;
    const short* gb = Bg + (size_t)srow * K + kt * 64 + scol;
#pragma unroll
    for (int rr = 0; rr < 4; ++rr) {
      *(sh8*)&sA[o + rr * 2048] = *(const sh8*)(ga + (size_t)(rr * 32) * K);
      *(sh8*)&sB[o + rr * 2048] = *(const sh8*)(gb + (size_t)(rr * 32) * K);
    }
    __syncthreads();
#pragma unroll
    for (int ks = 0; ks < 2; ++ks) {
      sh8 af[4], bfr[4];
      int rb = wr * 64 + (lane & 15);
      int cb = wc * 64 + (lane & 15);
      int kof = ks * 32 + (lane >> 4) * 8;
#pragma unroll
      for (int m = 0; m < 4; ++m) af[m] = *(const sh8*)&sA[(rb + m * 16) * 64 + kof];
#pragma unroll
      for (int n2 = 0; n2 < 4; ++n2) bfr[n2] = *(const sh8*)&sB[(cb + n2 * 16) * 64 + kof];
#pragma unroll
      for (int m = 0; m < 4; ++m)
#pragma unroll
        for (int n2 = 0; n2 < 4; ++n2)
          acc[m][n2] = __builtin_amdgcn_mfma_f32_16x16x32_bf16(af[m], bfr[n2], acc[m][n2], 0, 0, 0);
    }
    __syncthreads();
  }
  // epilogue: C/D layout col=lane&15, row=(lane>>4)*4+j
  int rbase = bm * 128 + wr * 64 + ((lane >> 4) << 2);
  int cbase = bn * 128 + wc * 64 + (lane & 15);
#pragma unroll
  for (int m = 0; m < 4; ++m) {
#pragma unroll
    for (int j = 0; j < 4; ++j) {
      int r = rbase + m * 16 + j;
      if (EPI == 3) {
        int b, d0, h0, w0; row_to_src(r0 + r, b, d0, h0, w0);
        size_t obase = (((size_t)b * D_ + d0) * C_) * WH + w0 * H_ + h0;
#pragma unroll
        for (int n2 = 0; n2 < 4; ++n2) {
          int cc = cbase + n2 * 16;
          ((float*)outv)[obase + (size_t)cc * WH] =
              acc[m][n2][j] + bias[cc] + res[(size_t)r * N + cc];
        }
      } else if (EPI == 2) {
#pragma unroll
        for (int n2 = 0; n2 < 4; ++n2) {
          int cc = cbase + n2 * 16;
          ((float*)outv)[(size_t)r * N + cc] =
              acc[m][n2][j] + bias[cc] + res[(size_t)r * N + cc];
        }
      } else {
#pragma unroll
        for (int n2 = 0; n2 < 4; ++n2) {
          int cc = cbase + n2 * 16;
          float v = acc[m][n2][j];
          if (bias) v += bias[cc];
          if (EPI == 1) v = 0.5f * v * (1.f + erff(v * 0.70710678118f));
          ((bf16*)outv)[(size_t)r * N + cc] = __float2bfloat16(v);
        }
      }
    }
  }
}

// ---------------- windowed attention (chunk-local qkv/aout) ----------------
__global__ __launch_bounds__(128) void k_attn(
    const bf16* __restrict__ qkv, const float* __restrict__ rpb,
    bf16* __restrict__ aout, int win0) {
  int blk = blockIdx.x;
  int wl = blk >> 3, h = blk & 7;
  int wg = win0 + wl;
  int widx = wg % NW1;
  int id = widx / 144; int rem = widx - id * 144; int ih = rem / 12, iw = rem - ih * 12;
  int tid = threadIdx.x;
  __shared__ __align__(16) float kk[NTOK][HD];
  __shared__ __align__(16) float vv[NTOK][HD];
  __shared__ int binf[NTOK];
  __shared__ int cinf[NTOK];
  const size_t base = (size_t)wl * NTOK * 768;
  for (int idx = tid; idx < NTOK * HD; idx += 128) {
    int row = idx >> 5, d = idx & 31;
    size_t rb = base + (size_t)row * 768 + h * 32 + d;
    kk[row][d] = __bfloat162float(qkv[rb + 256]);
    vv[row][d] = __bfloat162float(qkv[rb + 512]);
  }
  if (tid < NTOK) {
    int jd = tid / 49; int nr = tid - jd * 49; int jh = nr / 7, jw = nr - jh * 7;
    binf[tid] = jd * 169 + jh * 13 + jw;  // rel-pos base: idx = bi - bj + 253
    int sd = id * 2 + jd, sh = ih * 7 + jh, sw = iw * 7 + jw;
    int dg = (sd < 6) ? 0 : ((sd < 7) ? 1 : 2);
    int hg = (sh < 77) ? 0 : ((sh < 81) ? 1 : 2);
    int wgr = (sw < 77) ? 0 : ((sw < 81) ? 1 : 2);
    cinf[tid] = dg * 9 + hg * 3 + wgr;    // shift-mask region code
  }
  __syncthreads();
  if (tid >= NTOK) return;
  float q[HD];
  size_t qb = base + (size_t)tid * 768 + h * 32;
#pragma unroll
  for (int d = 0; d < HD; ++d) q[d] = __bfloat162float(qkv[qb + d]) * 0.17677669529663687f;
  int bi = binf[tid], ci = cinf[tid];
  float acc[HD] = {};
  float l = 0.f;
  for (int j = 0; j < NTOK; ++j) {
    float s = 0.f;
#pragma unroll
    for (int d = 0; d < HD; ++d) s += q[d] * kk[j][d];
    s += rpb[(bi - binf[j] + 253) * 8 + h];
    if (ci != cinf[j]) s -= 100.f;
    float p = __expf(s);
    l += p;
#pragma unroll
    for (int d = 0; d < HD; ++d) acc[d] += p * vv[j][d];
  }
  float inv = 1.f / l;
  size_t ob = ((size_t)wl * NTOK + tid) * C_ + h * 32;
#pragma unroll
  for (int d = 0; d < HD; ++d) aout[ob + d] = __float2bfloat16(acc[d] * inv);
}

// ---------------- residual + LN2: wave per row, float4 ----------------
template <bool XT>
__global__ __launch_bounds__(256) void k_xres_ln2v(
    const float* __restrict__ xin, const bf16* __restrict__ pout,
    const float* __restrict__ g, const float* __restrict__ bb,
    float* __restrict__ xres, bf16* __restrict__ ln2, int r0) {
  int rl = blockIdx.x * 4 + (threadIdx.x >> 6);
  int lane = threadIdx.x & 63;
  int b, d0, h0, w0; row_to_src(r0 + rl, b, d0, h0, w0);
  int c0 = lane * 4;
  float4 v;
  if (XT) {
    v = *(const float4*)(xin + (((size_t)(b * 8 + d0) * 84 + w0) * 84 + h0) * 256 + c0);
  } else {
    const float* p = xin + ((size_t)(b * 8 + d0) * 256 + c0) * WH + w0 * 84 + h0;
    v.x = p[0]; v.y = p[WH]; v.z = p[2 * WH]; v.w = p[3 * WH];
  }
  ushort4 pu = *(const ushort4*)(pout + (size_t)rl * 256 + c0);
  v.x += __bfloat162float(*(bf16*)&pu.x);
  v.y += __bfloat162float(*(bf16*)&pu.y);
  v.z += __bfloat162float(*(bf16*)&pu.z);
  v.w += __bfloat162float(*(bf16*)&pu.w);
  *(float4*)(xres + (size_t)rl * 256 + c0) = v;
  float s = v.x + v.y + v.z + v.w;
  float s2 = v.x * v.x + v.y * v.y + v.z * v.z + v.w * v.w;
#pragma unroll
  for (int off = 32; off; off >>= 1) { s += __shfl_xor(s, off, 64); s2 += __shfl_xor(s2, off, 64); }
  float mu = s * (1.f / 256.f);
  float var = s2 * (1.f / 256.f) - mu * mu;
  float rs = rsqrtf(var + 1e-5f);
  float4 gg = *(const float4*)(g + c0);
  float4 bv = *(const float4*)(bb + c0);
  bf16 tmp[4];
  tmp[0] = __float2bfloat16((v.x - mu) * rs * gg.x + bv.x);
  tmp[1] = __float2bfloat16((v.y - mu) * rs * gg.y + bv.y);
  tmp[2] = __float2bfloat16((v.z - mu) * rs * gg.z + bv.z);
  tmp[3] = __float2bfloat16((v.w - mu) * rs * gg.w + bv.w);
  *(ushort4*)(&ln2[(size_t)rl * 256 + c0]) = *(ushort4*)tmp;
}

// ---------------- final: windowed y (f32) -> (B,D,C,W,H), coalesced H lines ----------------
__global__ __launch_bounds__(256) void k_final(const float* __restrict__ y,
                                               float* __restrict__ out) {
  int bdw = blockIdx.x;
  int b = bdw / (D_ * W_);
  int rem = bdw - b * D_ * W_;
  int d0 = rem / W_, w0 = rem - d0 * W_;
  int tid = threadIdx.x;
  __shared__ float tile[84][65];
  __shared__ int rtab[84];
  if (tid < 84) {
    int h0 = tid;
    int sd = (d0 + 7) & 7;
    int sh = h0 + 81; if (sh >= 84) sh -= 84;
    int sw = w0 + 81; if (sw >= 84) sw -= 84;
    int id = sd >> 1, jd = sd & 1;
    int ih = sh / 7, jh = sh - ih * 7;
    int iw = sw / 7, jw = sw - iw * 7;
    rtab[h0] = (b * NW1 + id * 144 + ih * 12 + iw) * NTOK + jd * 49 + jh * 7 + jw;
  }
  __syncthreads();
  for (int c0 = 0; c0 < 256; c0 += 64) {
    for (int idx = tid; idx < 84 * 64; idx += 256) {
      int hh = idx >> 6, cc = idx & 63;
      tile[hh][cc] = y[(size_t)rtab[hh] * C_ + c0 + cc];
    }
    __syncthreads();
    for (int idx = tid; idx < 64 * 84; idx += 256) {
      int cc = idx / 84, hh = idx - cc * 84;
      out[((((size_t)b * D_ + d0) * C_ + (c0 + cc)) * W_ + w0) * H_ + hh] = tile[hh][cc];
    }
    __syncthreads();
  }
}

// ---------------- launch ----------------
extern "C" void kernel_launch(void* const* d_in, const int* in_sizes, int n_in,
                              void* d_out, int out_size, void* d_ws, size_t ws_size,
                              hipStream_t stream) {
  const float* x      = (const float*)d_in[0];
  const float* n1g    = (const float*)d_in[1];
  const float* n1b    = (const float*)d_in[2];
  const float* qkv_w  = (const float*)d_in[3];
  const float* rpb    = (const float*)d_in[4];
  const float* proj_w = (const float*)d_in[5];
  const float* proj_b = (const float*)d_in[6];
  const float* n2g    = (const float*)d_in[7];
  const float* n2b    = (const float*)d_in[8];
  const float* fc1_w  = (const float*)d_in[9];
  const float* fc1_b  = (const float*)d_in[10];
  const float* fc2_w  = (const float*)d_in[11];
  const float* fc2_b  = (const float*)d_in[12];
  float* out = (float*)d_out;

  // ---- weights (persistent) ----
  char* w = (char*)d_ws;
  size_t off = 0;
  bf16* wq = (bf16*)(w + off); off += (size_t)768 * 256 * 2;
  bf16* wp = (bf16*)(w + off); off += (size_t)256 * 256 * 2;
  bf16* w1 = (bf16*)(w + off); off += (size_t)1024 * 256 * 2;
  bf16* w2 = (bf16*)(w + off); off += (size_t)1024 * 256 * 2;
  size_t wbytes = off;

  // Mode A footprint: xt 115.6 + xw 57.8 + qreg 173.4 + xres 115.6 + hid/6 38.5 ~= 502MB
  size_t szXT = (size_t)MROWS * 1024;
  size_t szXW = (size_t)MROWS * 512;
  size_t szQR = (size_t)MROWS * 1536;
  size_t szXR = (size_t)MROWS * 1024;
  size_t szHC = (size_t)(MROWS / 6) * 2048;
  bool modeA = (wbytes + szXT + szXW + szQR + szXR + szHC + 1024 <= ws_size);

  // weights -> bf16
  k_f2b<<<(196608 + 255) / 256, 256, 0, stream>>>(qkv_w, wq, 196608);
  k_f2b<<<(65536 + 255) / 256, 256, 0, stream>>>(proj_w, wp, 65536);
  k_f2b<<<(262144 + 255) / 256, 256, 0, stream>>>(fc1_w, w1, 262144);
  k_f2b<<<(262144 + 255) / 256, 256, 0, stream>>>(fc2_w, w2, 262144);

  if (modeA) {
    float* xt  = (float*)(w + off);            off += szXT;
    bf16*  xw  = (bf16*)(w + off);             off += szXW;
    char*  qreg = w + off;                     off += szQR;
    float* xres = (float*)(w + off);           off += szXR;
    bf16*  hidc = (bf16*)(w + off);
    bf16* qkvb = (bf16*)qreg;
    bf16* aout = xw;                               // xw dead after qkv GEMM
    bf16* pout = (bf16*)qreg;                      // qkv dead after attn
    bf16* ln2b = (bf16*)(qreg + szXW);
    float* yb  = xt;                               // xt dead after xres_ln2

    k_xpose<<<2688, 256, 0, stream>>>(x, xt);
    k_ln1v<true><<<MROWS / 4, 256, 0, stream>>>(xt, n1g, n1b, xw, 0);
    k_gemm_bt<0><<<(MROWS / 128) * 6, 256, 0, stream>>>(
        xw, wq, MROWS, 768, 256, nullptr, nullptr, qkvb, 0);
    k_attn<<<NWIN * NH, 128, 0, stream>>>(qkvb, rpb, aout, 0);
    k_gemm_bt<0><<<(MROWS / 128) * 2, 256, 0, stream>>>(
        aout, wp, MROWS, 256, 256, proj_b, nullptr, pout, 0);
    k_xres_ln2v<true><<<MROWS / 4, 256, 0, stream>>>(xt, pout, n2g, n2b, xres, ln2b, 0);
    const int MC = MROWS / 6;   // 18816 rows = 147 row-tiles
    for (int ch = 0; ch < 6; ++ch) {
      size_t m0 = (size_t)ch * MC;
      k_gemm_bt<1><<<(MC / 128) * 8, 256, 0, stream>>>(
          ln2b + m0 * 256, w1, MC, 1024, 256, fc1_b, nullptr, hidc, 0);
      k_gemm_bt<2><<<(MC / 128) * 2, 256, 0, stream>>>(
          hidc, w2, MC, 256, 1024, fc2_b, xres + m0 * 256, yb + m0 * 256, 0);
    }
    k_final<<<B_ * D_ * W_, 256, 0, stream>>>(yb, out);
  } else {
    // ---- fallback: chunked, gather-based (R1 path) ----
    const int divs[6] = {18, 9, 6, 3, 2, 1};
    int ku = 1;
    for (int i = 0; i < 6; ++i) {
      if (wbytes + (size_t)divs[i] * MUNIT * 5120 + 1024 <= ws_size) { ku = divs[i]; break; }
    }
    const int Mc = ku * MUNIT;
    const int nch = 18 / ku;
    const int nwc = Mc / NTOK;
    bf16*  xw   = (bf16*)(w + off);            off += (size_t)Mc * 512;
    char*  qreg = w + off;                     off += (size_t)Mc * 1536;
    float* xres = (float*)(w + off);           off += (size_t)Mc * 1024;
    bf16*  hid  = (bf16*)(w + off);
    bf16* qkvb = (bf16*)qreg;
    bf16* aout = xw;
    bf16* pout = (bf16*)qreg;
    bf16* ln2b = (bf16*)(qreg + (size_t)Mc * 512);
    for (int ch = 0; ch < nch; ++ch) {
      int r0 = ch * Mc;
      int win0 = ch * nwc;
      k_ln1v<false><<<Mc / 4, 256, 0, stream>>>(x, n1g, n1b, xw, r0);
      k_gemm_bt<0><<<(Mc / 128) * 6, 256, 0, stream>>>(
          xw, wq, Mc, 768, 256, nullptr, nullptr, qkvb, 0);
      k_attn<<<nwc * NH, 128, 0, stream>>>(qkvb, rpb, aout, win0);
      k_gemm_bt<0><<<(Mc / 128) * 2, 256, 0, stream>>>(
          aout, wp, Mc, 256, 256, proj_b, nullptr, pout, 0);
      k_xres_ln2v<false><<<Mc / 4, 256, 0, stream>>>(x, pout, n2g, n2b, xres, ln2b, r0);
      k_gemm_bt<1><<<(Mc / 128) * 8, 256, 0, stream>>>(
          ln2b, w1, Mc, 1024, 256, fc1_b, nullptr, hid, 0);
      k_gemm_bt<3><<<(Mc / 128) * 2, 256, 0, stream>>>(
          hid, w2, Mc, 256, 1024, fc2_b, xres, out, r0);
    }
  }
}

// Round 4
// 1272.499 us; speedup vs baseline: 1.6035x; 1.5534x over previous
//
#include <hip/hip_runtime.h>
#include <hip/hip_bf16.h>
#include <cstdint>
#include <cstddef>

// ---- problem constants ----
#define B_   2
#define D_   8
#define C_   256
#define W_   84
#define H_   84
#define NH   8
#define HD   32
#define NTOK 98
#define WH   7056        // W_*H_
#define M2   56448       // rows per chunk = 576 windows * 98 (441 * 128)
#define NWC  576         // windows per chunk

typedef __attribute__((ext_vector_type(8))) short sh8;
typedef __attribute__((ext_vector_type(4))) float f32x4;
typedef __hip_bfloat16 bf16;

// ---------------- fp32 -> bf16 weight convert ----------------
__global__ __launch_bounds__(256) void k_f2b(const float* __restrict__ in,
                                             bf16* __restrict__ out, int n) {
  int i = blockIdx.x * 256 + threadIdx.x;
  if (i < n) out[i] = __float2bfloat16(in[i]);
}

// inverse map (shared by xpose and final): src/dst plane (b,d0,w0,h0) -> chunk-local row
__device__ __forceinline__ int inv_row(int b, int d0, int w0, int h0) {
  int sd = (d0 + 7) & 7;
  int lid = (sd >> 1) & 1, jd = sd & 1;
  int sh = h0 + 81; if (sh >= 84) sh -= 84;
  int sw = w0 + 81; if (sw >= 84) sw -= 84;
  int ih = sh / 7, jh = sh - ih * 7;
  int iw = sw / 7, jw = sw - iw * 7;
  return (b * 288 + lid * 144 + ih * 12 + iw) * 98 + jd * 49 + jh * 7 + jw;
}

// ---------------- x (B,D,C,W,H) -> xtw windowed rows x 256, f32, coalesced ----------------
__global__ __launch_bounds__(256) void k_xpose_w(const float* __restrict__ x,
                                                 float* __restrict__ xtw, int cchunk) {
  int blk = blockIdx.x;            // 1344 = 2ch * 84w * 4i * 2b
  int ch = blk & 1;
  int t = blk >> 1;
  int w0 = t % 84;
  int t2 = t / 84;
  int i = t2 & 3, b = t2 >> 2;
  int d0 = (cchunk * 4 + 1 + i) & 7;
  __shared__ float tile[128][85];
  __shared__ int rtab[84];
  int tid = threadIdx.x;
  if (tid < 84) rtab[tid] = inv_row(b, d0, w0, tid);
  const float* src = x + ((size_t)(b * 8 + d0) * 256 + ch * 128) * WH + w0 * 84;
  for (int idx = tid; idx < 128 * 21; idx += 256) {
    int c = idx / 21, h4 = idx - c * 21;
    float4 v = *(const float4*)(src + (size_t)c * WH + h4 * 4);
    tile[c][h4 * 4 + 0] = v.x; tile[c][h4 * 4 + 1] = v.y;
    tile[c][h4 * 4 + 2] = v.z; tile[c][h4 * 4 + 3] = v.w;
  }
  __syncthreads();
  for (int idx = tid; idx < 84 * 128; idx += 256) {
    int h = idx >> 7, cc = idx & 127;
    xtw[(size_t)rtab[h] * 256 + ch * 128 + cc] = tile[cc][h];
  }
}

// ---------------- LN1: linear streaming, wave per row ----------------
__global__ __launch_bounds__(256) void k_ln1_lin(
    const float* __restrict__ xtw, const float* __restrict__ g,
    const float* __restrict__ bb, bf16* __restrict__ xw) {
  int rl = blockIdx.x * 4 + (threadIdx.x >> 6);
  int lane = threadIdx.x & 63;
  int c0 = lane * 4;
  float4 v = *(const float4*)(xtw + (size_t)rl * 256 + c0);
  float s = v.x + v.y + v.z + v.w;
  float s2 = v.x * v.x + v.y * v.y + v.z * v.z + v.w * v.w;
#pragma unroll
  for (int off = 32; off; off >>= 1) { s += __shfl_xor(s, off, 64); s2 += __shfl_xor(s2, off, 64); }
  float mu = s * (1.f / 256.f);
  float var = s2 * (1.f / 256.f) - mu * mu;
  float rs = rsqrtf(var + 1e-5f);
  float4 gg = *(const float4*)(g + c0);
  float4 bv = *(const float4*)(bb + c0);
  bf16 tmp[4];
  tmp[0] = __float2bfloat16((v.x - mu) * rs * gg.x + bv.x);
  tmp[1] = __float2bfloat16((v.y - mu) * rs * gg.y + bv.y);
  tmp[2] = __float2bfloat16((v.z - mu) * rs * gg.z + bv.z);
  tmp[3] = __float2bfloat16((v.w - mu) * rs * gg.w + bv.w);
  *(ushort4*)(&xw[(size_t)rl * 256 + c0]) = *(ushort4*)tmp;
}

// ---------------- bf16 B^T GEMM: out = A(MxK) @ Bw(NxK)^T ----------------
// EPI 0: (+bias) -> bf16   EPI 1: +bias, GELU -> bf16   EPI 2: +bias +res -> f32 linear
template <int EPI>
__global__ __launch_bounds__(256) void k_gemm_bt(
    const bf16* __restrict__ A, const bf16* __restrict__ Bw,
    int M, int N, int K,
    const float* __restrict__ bias, const float* __restrict__ res,
    void* __restrict__ outv) {
  __shared__ __align__(16) short sA[128 * 64];
  __shared__ __align__(16) short sB[128 * 64];
  int nbn = N >> 7;
  int bm = blockIdx.x / nbn, bn = blockIdx.x - bm * nbn;
  int tid = threadIdx.x;
  int lane = tid & 63, wv = tid >> 6;
  int wr = wv >> 1, wc = wv & 1;
  f32x4 acc[4][4] = {};
  const short* Ag = (const short*)A + (size_t)bm * 128 * K;
  const short* Bg = (const short*)Bw + (size_t)bn * 128 * K;
  int o = tid << 3;
  int srow = o >> 6, scol = o & 63;
  int nk = K >> 6;
  for (int kt = 0; kt < nk; ++kt) {
    const short* ga = Ag + (size_t)srow * K + kt * 64 + scol;
    const short* gb = Bg + (size_t)srow * K + kt * 64 + scol;
#pragma unroll
    for (int rr = 0; rr < 4; ++rr) {
      *(sh8*)&sA[o + rr * 2048] = *(const sh8*)(ga + (size_t)(rr * 32) * K);
      *(sh8*)&sB[o + rr * 2048] = *(const sh8*)(gb + (size_t)(rr * 32) * K);
    }
    __syncthreads();
#pragma unroll
    for (int ks = 0; ks < 2; ++ks) {
      sh8 af[4], bfr[4];
      int rb = wr * 64 + (lane & 15);
      int cb = wc * 64 + (lane & 15);
      int kof = ks * 32 + (lane >> 4) * 8;
#pragma unroll
      for (int m = 0; m < 4; ++m) af[m] = *(const sh8*)&sA[(rb + m * 16) * 64 + kof];
#pragma unroll
      for (int n2 = 0; n2 < 4; ++n2) bfr[n2] = *(const sh8*)&sB[(cb + n2 * 16) * 64 + kof];
#pragma unroll
      for (int m = 0; m < 4; ++m)
#pragma unroll
        for (int n2 = 0; n2 < 4; ++n2)
          acc[m][n2] = __builtin_amdgcn_mfma_f32_16x16x32_bf16(af[m], bfr[n2], acc[m][n2], 0, 0, 0);
    }
    __syncthreads();
  }
  int rbase = bm * 128 + wr * 64 + ((lane >> 4) << 2);
  int cbase = bn * 128 + wc * 64 + (lane & 15);
#pragma unroll
  for (int m = 0; m < 4; ++m) {
#pragma unroll
    for (int j = 0; j < 4; ++j) {
      int r = rbase + m * 16 + j;
#pragma unroll
      for (int n2 = 0; n2 < 4; ++n2) {
        int cc = cbase + n2 * 16;
        float v = acc[m][n2][j];
        if (EPI == 2) {
          v += bias[cc] + res[(size_t)r * N + cc];
          ((float*)outv)[(size_t)r * N + cc] = v;
        } else {
          if (bias) v += bias[cc];
          if (EPI == 1) v = 0.5f * v * (1.f + erff(v * 0.70710678118f));
          ((bf16*)outv)[(size_t)r * N + cc] = __float2bfloat16(v);
        }
      }
    }
  }
}

// ---------------- windowed attention (chunk-local) ----------------
__global__ __launch_bounds__(128) void k_attn(
    const bf16* __restrict__ qkv, const float* __restrict__ rpb,
    bf16* __restrict__ aout, int idbase) {
  int blk = blockIdx.x;
  int wl = blk >> 3, h = blk & 7;
  int lid = (wl / 144) & 1;
  int id = idbase + lid;
  int rem = wl % 144;
  int ih = rem / 12, iw = rem - ih * 12;
  int tid = threadIdx.x;
  __shared__ __align__(16) float kk[NTOK][HD];
  __shared__ __align__(16) float vv[NTOK][HD];
  __shared__ int binf[NTOK];
  __shared__ int cinf[NTOK];
  const size_t base = (size_t)wl * NTOK * 768;
  for (int idx = tid; idx < NTOK * 8; idx += 128) {
    int row = idx >> 3, d4 = (idx & 7) * 4;
    size_t rb = base + (size_t)row * 768 + h * 32 + d4;
    ushort4 ku = *(const ushort4*)&qkv[rb + 256];
    ushort4 vu = *(const ushort4*)&qkv[rb + 512];
    kk[row][d4 + 0] = __bfloat162float(*(bf16*)&ku.x);
    kk[row][d4 + 1] = __bfloat162float(*(bf16*)&ku.y);
    kk[row][d4 + 2] = __bfloat162float(*(bf16*)&ku.z);
    kk[row][d4 + 3] = __bfloat162float(*(bf16*)&ku.w);
    vv[row][d4 + 0] = __bfloat162float(*(bf16*)&vu.x);
    vv[row][d4 + 1] = __bfloat162float(*(bf16*)&vu.y);
    vv[row][d4 + 2] = __bfloat162float(*(bf16*)&vu.z);
    vv[row][d4 + 3] = __bfloat162float(*(bf16*)&vu.w);
  }
  if (tid < NTOK) {
    int jd = tid / 49; int nr = tid - jd * 49; int jh = nr / 7, jw = nr - jh * 7;
    binf[tid] = jd * 169 + jh * 13 + jw;  // rel-pos base: idx = bi - bj + 253
    int sd = id * 2 + jd, sh = ih * 7 + jh, sw = iw * 7 + jw;
    int dg = (sd < 6) ? 0 : ((sd < 7) ? 1 : 2);
    int hg = (sh < 77) ? 0 : ((sh < 81) ? 1 : 2);
    int wgr = (sw < 77) ? 0 : ((sw < 81) ? 1 : 2);
    cinf[tid] = dg * 9 + hg * 3 + wgr;    // shift-mask region code
  }
  __syncthreads();
  if (tid >= NTOK) return;
  float q[HD];
  size_t qb = base + (size_t)tid * 768 + h * 32;
#pragma unroll
  for (int dq = 0; dq < 8; ++dq) {
    ushort4 qu = *(const ushort4*)&qkv[qb + dq * 4];
    q[dq * 4 + 0] = __bfloat162float(*(bf16*)&qu.x) * 0.17677669529663687f;
    q[dq * 4 + 1] = __bfloat162float(*(bf16*)&qu.y) * 0.17677669529663687f;
    q[dq * 4 + 2] = __bfloat162float(*(bf16*)&qu.z) * 0.17677669529663687f;
    q[dq * 4 + 3] = __bfloat162float(*(bf16*)&qu.w) * 0.17677669529663687f;
  }
  int bi = binf[tid], ci = cinf[tid];
  float acc[HD] = {};
  float l = 0.f;
  for (int j = 0; j < NTOK; ++j) {
    float s = 0.f;
#pragma unroll
    for (int d = 0; d < HD; ++d) s += q[d] * kk[j][d];
    s += rpb[(bi - binf[j] + 253) * 8 + h];
    if (ci != cinf[j]) s -= 100.f;
    float p = __expf(s);
    l += p;
#pragma unroll
    for (int d = 0; d < HD; ++d) acc[d] += p * vv[j][d];
  }
  float inv = 1.f / l;
  size_t ob = ((size_t)wl * NTOK + tid) * C_ + h * 32;
#pragma unroll
  for (int dg4 = 0; dg4 < 8; ++dg4) {
    bf16 tmp[4];
    tmp[0] = __float2bfloat16(acc[dg4 * 4 + 0] * inv);
    tmp[1] = __float2bfloat16(acc[dg4 * 4 + 1] * inv);
    tmp[2] = __float2bfloat16(acc[dg4 * 4 + 2] * inv);
    tmp[3] = __float2bfloat16(acc[dg4 * 4 + 3] * inv);
    *(ushort4*)(&aout[ob + dg4 * 4]) = *(ushort4*)tmp;
  }
}

// ---------------- residual + LN2: linear streaming ----------------
__global__ __launch_bounds__(256) void k_xres_ln2_lin(
    const float* __restrict__ xtw, const bf16* __restrict__ pout,
    const float* __restrict__ g, const float* __restrict__ bb,
    float* __restrict__ xres, bf16* __restrict__ ln2) {
  int rl = blockIdx.x * 4 + (threadIdx.x >> 6);
  int lane = threadIdx.x & 63;
  int c0 = lane * 4;
  float4 v = *(const float4*)(xtw + (size_t)rl * 256 + c0);
  ushort4 pu = *(const ushort4*)(pout + (size_t)rl * 256 + c0);
  v.x += __bfloat162float(*(bf16*)&pu.x);
  v.y += __bfloat162float(*(bf16*)&pu.y);
  v.z += __bfloat162float(*(bf16*)&pu.z);
  v.w += __bfloat162float(*(bf16*)&pu.w);
  *(float4*)(xres + (size_t)rl * 256 + c0) = v;
  float s = v.x + v.y + v.z + v.w;
  float s2 = v.x * v.x + v.y * v.y + v.z * v.z + v.w * v.w;
#pragma unroll
  for (int off = 32; off; off >>= 1) { s += __shfl_xor(s, off, 64); s2 += __shfl_xor(s2, off, 64); }
  float mu = s * (1.f / 256.f);
  float var = s2 * (1.f / 256.f) - mu * mu;
  float rs = rsqrtf(var + 1e-5f);
  float4 gg = *(const float4*)(g + c0);
  float4 bv = *(const float4*)(bb + c0);
  bf16 tmp[4];
  tmp[0] = __float2bfloat16((v.x - mu) * rs * gg.x + bv.x);
  tmp[1] = __float2bfloat16((v.y - mu) * rs * gg.y + bv.y);
  tmp[2] = __float2bfloat16((v.z - mu) * rs * gg.z + bv.z);
  tmp[3] = __float2bfloat16((v.w - mu) * rs * gg.w + bv.w);
  *(ushort4*)(&ln2[(size_t)rl * 256 + c0]) = *(ushort4*)tmp;
}

// ---------------- final: chunk-local y (f32 windowed) -> (B,D,C,W,H) ----------------
__global__ __launch_bounds__(256) void k_final_c(const float* __restrict__ y,
                                                 float* __restrict__ out, int cchunk) {
  int t = blockIdx.x;              // 672 = 84w * 4i * 2b
  int w0 = t % 84;
  int t2 = t / 84;
  int i = t2 & 3, b = t2 >> 2;
  int d0 = (cchunk * 4 + 1 + i) & 7;
  __shared__ float tile[84][65];
  __shared__ int rtab[84];
  int tid = threadIdx.x;
  if (tid < 84) rtab[tid] = inv_row(b, d0, w0, tid);
  __syncthreads();
  for (int c0 = 0; c0 < 256; c0 += 64) {
    for (int idx = tid; idx < 84 * 64; idx += 256) {
      int hh = idx >> 6, cc = idx & 63;
      tile[hh][cc] = y[(size_t)rtab[hh] * 256 + c0 + cc];
    }
    __syncthreads();
    for (int idx = tid; idx < 64 * 84; idx += 256) {
      int cc = idx / 84, hh = idx - cc * 84;
      out[((((size_t)b * 8 + d0) * 256 + c0 + cc) * 84 + w0) * 84 + hh] = tile[hh][cc];
    }
    __syncthreads();
  }
}

// ---------------- launch ----------------
extern "C" void kernel_launch(void* const* d_in, const int* in_sizes, int n_in,
                              void* d_out, int out_size, void* d_ws, size_t ws_size,
                              hipStream_t stream) {
  const float* x      = (const float*)d_in[0];
  const float* n1g    = (const float*)d_in[1];
  const float* n1b    = (const float*)d_in[2];
  const float* qkv_w  = (const float*)d_in[3];
  const float* rpb    = (const float*)d_in[4];
  const float* proj_w = (const float*)d_in[5];
  const float* proj_b = (const float*)d_in[6];
  const float* n2g    = (const float*)d_in[7];
  const float* n2b    = (const float*)d_in[8];
  const float* fc1_w  = (const float*)d_in[9];
  const float* fc1_b  = (const float*)d_in[10];
  const float* fc2_w  = (const float*)d_in[11];
  const float* fc2_b  = (const float*)d_in[12];
  float* out = (float*)d_out;

  // ---- weights ----
  char* w = (char*)d_ws;
  size_t off = 0;
  bf16* wq = (bf16*)(w + off); off += (size_t)768 * 256 * 2;
  bf16* wp = (bf16*)(w + off); off += (size_t)256 * 256 * 2;
  bf16* w1 = (bf16*)(w + off); off += (size_t)1024 * 256 * 2;
  bf16* w2 = (bf16*)(w + off); off += (size_t)1024 * 256 * 2;

  // ---- per-chunk buffers (footprint <= ~271 MB; known-good budget 290 MB) ----
  float* xtw  = (float*)(w + off); off += (size_t)M2 * 1024;    // 57.8 MB (also y)
  bf16*  xw   = (bf16*)(w + off);  off += (size_t)M2 * 512;     // 28.9 MB (also aout)
  char*  qreg = w + off;           off += (size_t)M2 * 1536;    // 86.7 MB
  float* xres = (float*)(w + off); off += (size_t)M2 * 1024;    // 57.8 MB
  bf16*  hid  = (bf16*)(w + off);                               // sub-chunk sized
  bf16* qkvb = (bf16*)qreg;
  bf16* aout = xw;
  bf16* pout = (bf16*)qreg;
  bf16* ln2b = (bf16*)(qreg + (size_t)M2 * 512);
  float* ybuf = xtw;

  // MLP sub-chunk tiers: 147/49/21 row-tiles (hid = 38.5/12.8/5.5 MB)
  int subTiles = 21;
  if (off + (size_t)147 * 128 * 2048 + 1024 <= ws_size) subTiles = 147;
  else if (off + (size_t)49 * 128 * 2048 + 1024 <= ws_size) subTiles = 49;
  const int nsub = 441 / subTiles;
  const int MSUB = subTiles * 128;

  // weights -> bf16
  k_f2b<<<(196608 + 255) / 256, 256, 0, stream>>>(qkv_w, wq, 196608);
  k_f2b<<<(65536 + 255) / 256, 256, 0, stream>>>(proj_w, wp, 65536);
  k_f2b<<<(262144 + 255) / 256, 256, 0, stream>>>(fc1_w, w1, 262144);
  k_f2b<<<(262144 + 255) / 256, 256, 0, stream>>>(fc2_w, w2, 262144);

  for (int c = 0; c < 2; ++c) {
    k_xpose_w<<<1344, 256, 0, stream>>>(x, xtw, c);
    k_ln1_lin<<<M2 / 4, 256, 0, stream>>>(xtw, n1g, n1b, xw);
    k_gemm_bt<0><<<441 * 6, 256, 0, stream>>>(xw, wq, M2, 768, 256, nullptr, nullptr, qkvb);
    k_attn<<<NWC * NH, 128, 0, stream>>>(qkvb, rpb, aout, 2 * c);
    k_gemm_bt<0><<<441 * 2, 256, 0, stream>>>(aout, wp, M2, 256, 256, proj_b, nullptr, pout);
    k_xres_ln2_lin<<<M2 / 4, 256, 0, stream>>>(xtw, pout, n2g, n2b, xres, ln2b);
    for (int s = 0; s < nsub; ++s) {
      size_t m0 = (size_t)s * MSUB;
      k_gemm_bt<1><<<subTiles * 8, 256, 0, stream>>>(
          ln2b + m0 * 256, w1, MSUB, 1024, 256, fc1_b, nullptr, hid);
      k_gemm_bt<2><<<subTiles * 2, 256, 0, stream>>>(
          hid, w2, MSUB, 256, 1024, fc2_b, xres + m0 * 256, ybuf + m0 * 256);
    }
    k_final_c<<<672, 256, 0, stream>>>(ybuf, out, c);
  }
}

// Round 5
// 1081.073 us; speedup vs baseline: 1.8875x; 1.1771x over previous
//
#include <hip/hip_runtime.h>
#include <hip/hip_bf16.h>
#include <cstdint>
#include <cstddef>

// ---- problem constants ----
#define B_   2
#define D_   8
#define C_   256
#define W_   84
#define H_   84
#define NH   8
#define HD   32
#define NTOK 98
#define WH   7056        // W_*H_
#define M2   56448       // rows per chunk = 576 windows * 98 (441 * 128)
#define NWC  576         // windows per chunk

typedef __attribute__((ext_vector_type(8))) short sh8;
typedef __attribute__((ext_vector_type(4))) float f32x4;
typedef __hip_bfloat16 bf16;

// ---------------- fp32 -> bf16 weight convert ----------------
__global__ __launch_bounds__(256) void k_f2b(const float* __restrict__ in,
                                             bf16* __restrict__ out, int n) {
  int i = blockIdx.x * 256 + threadIdx.x;
  if (i < n) out[i] = __float2bfloat16(in[i]);
}

// ---------------- bias+mask table: [8 cls][8 h][112][112] f32 ----------------
__global__ __launch_bounds__(256) void k_bias(const float* __restrict__ rpb,
                                              float* __restrict__ tbl) {
  int cls = blockIdx.x >> 3, h = blockIdx.x & 7;
  int dB = cls >> 2, hB = (cls >> 1) & 1, wB = cls & 1;
  for (int idx = threadIdx.x; idx < 112 * 112; idx += 256) {
    int r = idx / 112, c = idx - (idx / 112) * 112;
    int rt = r < 98 ? r : 97, ct = c < 98 ? c : 97;
    int jdr = rt / 49, remr = rt % 49, jhr = remr / 7, jwr = remr % 7;
    int jdc = ct / 49, remc = ct % 49, jhc = remc / 7, jwc = remc % 7;
    int bir = jdr * 169 + jhr * 13 + jwr, bic = jdc * 169 + jhc * 13 + jwc;
    int dgr = dB ? ((6 + jdr) < 7 ? 1 : 2) : 0;
    int hgr = hB ? ((77 + jhr) < 81 ? 1 : 2) : 0;
    int wgr = wB ? ((77 + jwr) < 81 ? 1 : 2) : 0;
    int dgc = dB ? ((6 + jdc) < 7 ? 1 : 2) : 0;
    int hgc = hB ? ((77 + jhc) < 81 ? 1 : 2) : 0;
    int wgc = wB ? ((77 + jwc) < 81 ? 1 : 2) : 0;
    int cir = dgr * 9 + hgr * 3 + wgr, cic = dgc * 9 + hgc * 3 + wgc;
    float v = rpb[(bir - bic + 253) * 8 + h] + (cir == cic ? 0.f : -100.f);
    tbl[((size_t)(cls * 8 + h) * 112 + r) * 112 + c] = v;
  }
}

// inverse map: src/dst plane (b,d0,w0,h0) -> chunk-local row
__device__ __forceinline__ int inv_row(int b, int d0, int w0, int h0) {
  int sd = (d0 + 7) & 7;
  int lid = (sd >> 1) & 1, jd = sd & 1;
  int sh = h0 + 81; if (sh >= 84) sh -= 84;
  int sw = w0 + 81; if (sw >= 84) sw -= 84;
  int ih = sh / 7, jh = sh - ih * 7;
  int iw = sw / 7, jw = sw - iw * 7;
  return (b * 288 + lid * 144 + ih * 12 + iw) * 98 + jd * 49 + jh * 7 + jw;
}

// ---------------- x (B,D,C,W,H) -> xtw windowed rows x 256, f32 ----------------
__global__ __launch_bounds__(256) void k_xpose_w(const float* __restrict__ x,
                                                 float* __restrict__ xtw, int cchunk) {
  int blk = blockIdx.x;            // 1344 = 2ch * 84w * 4i * 2b
  int ch = blk & 1;
  int t = blk >> 1;
  int w0 = t % 84;
  int t2 = t / 84;
  int i = t2 & 3, b = t2 >> 2;
  int d0 = (cchunk * 4 + 1 + i) & 7;
  __shared__ float tile[128][85];
  __shared__ int rtab[84];
  int tid = threadIdx.x;
  if (tid < 84) rtab[tid] = inv_row(b, d0, w0, tid);
  const float* src = x + ((size_t)(b * 8 + d0) * 256 + ch * 128) * WH + w0 * 84;
  for (int idx = tid; idx < 128 * 21; idx += 256) {
    int c = idx / 21, h4 = idx - c * 21;
    float4 v = *(const float4*)(src + (size_t)c * WH + h4 * 4);
    tile[c][h4 * 4 + 0] = v.x; tile[c][h4 * 4 + 1] = v.y;
    tile[c][h4 * 4 + 2] = v.z; tile[c][h4 * 4 + 3] = v.w;
  }
  __syncthreads();
  for (int idx = tid; idx < 84 * 128; idx += 256) {
    int h = idx >> 7, cc = idx & 127;
    xtw[(size_t)rtab[h] * 256 + ch * 128 + cc] = tile[cc][h];
  }
}

// ---------------- LN1: linear streaming ----------------
__global__ __launch_bounds__(256) void k_ln1_lin(
    const float* __restrict__ xtw, const float* __restrict__ g,
    const float* __restrict__ bb, bf16* __restrict__ xw) {
  int rl = blockIdx.x * 4 + (threadIdx.x >> 6);
  int lane = threadIdx.x & 63;
  int c0 = lane * 4;
  float4 v = *(const float4*)(xtw + (size_t)rl * 256 + c0);
  float s = v.x + v.y + v.z + v.w;
  float s2 = v.x * v.x + v.y * v.y + v.z * v.z + v.w * v.w;
#pragma unroll
  for (int off = 32; off; off >>= 1) { s += __shfl_xor(s, off, 64); s2 += __shfl_xor(s2, off, 64); }
  float mu = s * (1.f / 256.f);
  float var = s2 * (1.f / 256.f) - mu * mu;
  float rs = rsqrtf(var + 1e-5f);
  float4 gg = *(const float4*)(g + c0);
  float4 bv = *(const float4*)(bb + c0);
  bf16 tmp[4];
  tmp[0] = __float2bfloat16((v.x - mu) * rs * gg.x + bv.x);
  tmp[1] = __float2bfloat16((v.y - mu) * rs * gg.y + bv.y);
  tmp[2] = __float2bfloat16((v.z - mu) * rs * gg.z + bv.z);
  tmp[3] = __float2bfloat16((v.w - mu) * rs * gg.w + bv.w);
  *(ushort4*)(&xw[(size_t)rl * 256 + c0]) = *(ushort4*)tmp;
}

// ---------------- bf16 B^T GEMM with global_load_lds staging ----------------
// EPI 0: (+bias) -> bf16   EPI 1: +bias, GELU -> bf16   EPI 2: +bias +res -> f32 linear
template <int EPI>
__global__ __launch_bounds__(256) void k_gemm_bt(
    const bf16* __restrict__ A, const bf16* __restrict__ Bw,
    int M, int N, int K,
    const float* __restrict__ bias, const float* __restrict__ res,
    void* __restrict__ outv) {
  __shared__ __align__(16) short sA[128 * 64];
  __shared__ __align__(16) short sB[128 * 64];
  int nbn = N >> 7;
  int bm = blockIdx.x / nbn, bn = blockIdx.x - bm * nbn;
  int tid = threadIdx.x;
  int lane = tid & 63, wv = tid >> 6;
  int wr = wv >> 1, wc = wv & 1;
  f32x4 acc[4][4] = {};
  const short* Ag = (const short*)A + (size_t)bm * 128 * K;
  const short* Bg = (const short*)Bw + (size_t)bn * 128 * K;
  // staging geometry: wave wv covers rows wv*32..+31; lane l -> row l>>3, col (l&7)*8
  int rA = wv * 32 + (lane >> 3);
  int cA = (lane & 7) * 8;
  int nk = K >> 6;
  for (int kt = 0; kt < nk; ++kt) {
    const short* ga = Ag + (size_t)rA * K + kt * 64 + cA;
    const short* gb = Bg + (size_t)rA * K + kt * 64 + cA;
#pragma unroll
    for (int rr = 0; rr < 4; ++rr) {
      __builtin_amdgcn_global_load_lds(
          (const __attribute__((address_space(1))) void*)(ga + (size_t)rr * 8 * K),
          (__attribute__((address_space(3))) void*)&sA[(wv * 32 + rr * 8) * 64], 16, 0, 0);
      __builtin_amdgcn_global_load_lds(
          (const __attribute__((address_space(1))) void*)(gb + (size_t)rr * 8 * K),
          (__attribute__((address_space(3))) void*)&sB[(wv * 32 + rr * 8) * 64], 16, 0, 0);
    }
    __syncthreads();
#pragma unroll
    for (int ks = 0; ks < 2; ++ks) {
      sh8 af[4], bfr[4];
      int rb = wr * 64 + (lane & 15);
      int cb = wc * 64 + (lane & 15);
      int kof = ks * 32 + (lane >> 4) * 8;
#pragma unroll
      for (int m = 0; m < 4; ++m) af[m] = *(const sh8*)&sA[(rb + m * 16) * 64 + kof];
#pragma unroll
      for (int n2 = 0; n2 < 4; ++n2) bfr[n2] = *(const sh8*)&sB[(cb + n2 * 16) * 64 + kof];
#pragma unroll
      for (int m = 0; m < 4; ++m)
#pragma unroll
        for (int n2 = 0; n2 < 4; ++n2)
          acc[m][n2] = __builtin_amdgcn_mfma_f32_16x16x32_bf16(af[m], bfr[n2], acc[m][n2], 0, 0, 0);
    }
    __syncthreads();
  }
  int rbase = bm * 128 + wr * 64 + ((lane >> 4) << 2);
  int cbase = bn * 128 + wc * 64 + (lane & 15);
#pragma unroll
  for (int m = 0; m < 4; ++m) {
#pragma unroll
    for (int j = 0; j < 4; ++j) {
      int r = rbase + m * 16 + j;
#pragma unroll
      for (int n2 = 0; n2 < 4; ++n2) {
        int cc = cbase + n2 * 16;
        float v = acc[m][n2][j];
        if (EPI == 2) {
          v += bias[cc] + res[(size_t)r * N + cc];
          ((float*)outv)[(size_t)r * N + cc] = v;
        } else {
          if (bias) v += bias[cc];
          if (EPI == 1) v = 0.5f * v * (1.f + erff(v * 0.70710678118f));
          ((bf16*)outv)[(size_t)r * N + cc] = __float2bfloat16(v);
        }
      }
    }
  }
}

// ---------------- MFMA windowed attention: 1 wave per (window, head) ----------------
// Fragment layout (verified in GEMM): A/B-frag lane L holds row (L&15), k=(L>>4)*8..+7;
// D lane L holds rows (L>>4)*4+{0..3}, col (L&15).
__global__ __launch_bounds__(64) void k_attn_mfma(
    const bf16* __restrict__ qkv, const float* __restrict__ tbl,
    bf16* __restrict__ aout, int idbase) {
  int blk = blockIdx.x;
  int wl = blk >> 3, h = blk & 7;
  int lid = (wl / 144) & 1;
  int id = idbase + lid;
  int rem = wl % 144;
  int ih = rem / 12, iw = rem - ih * 12;
  int cls = ((id == 3) ? 4 : 0) + ((ih == 11) ? 2 : 0) + ((iw == 11) ? 1 : 0);
  const float* bt = tbl + (size_t)(cls * 8 + h) * 112 * 112;
  int lane = threadIdx.x;
  __shared__ __align__(16) short vt[32][136];   // V^T, padded (272B rows)
  __shared__ __align__(16) short pb[16][136];   // P band
  // zero LDS (pad regions must be 0)
  sh8 z = {};
  for (int i = lane; i < 544; i += 64) *((sh8*)&vt[0][0] + i) = z;
  for (int i = lane; i < 272; i += 64) *((sh8*)&pb[0][0] + i) = z;
  __syncthreads();
  const size_t base = (size_t)wl * NTOK * 768;
  // stage V^T: V[c][d] -> vt[d][c]
  for (int i = lane; i < 98 * 8; i += 64) {
    int c = i >> 3, d4 = (i & 7) * 4;
    ushort4 vu = *(const ushort4*)&qkv[base + (size_t)c * 768 + 512 + h * 32 + d4];
    vt[d4 + 0][c] = (short)vu.x; vt[d4 + 1][c] = (short)vu.y;
    vt[d4 + 2][c] = (short)vu.z; vt[d4 + 3][c] = (short)vu.w;
  }
  int kq = (lane >> 4) * 8;
  // K fragments (rows 98..111 read garbage; masked later)
  sh8 kf[7];
#pragma unroll
  for (int jt = 0; jt < 7; ++jt) {
    int c = jt * 16 + (lane & 15);
    kf[jt] = *(const sh8*)&qkv[base + (size_t)c * 768 + 256 + h * 32 + kq];
  }
  __syncthreads();
  // V^T fragments (loop-invariant)
  sh8 vb[2][4];
#pragma unroll
  for (int dt = 0; dt < 2; ++dt)
#pragma unroll
    for (int k2 = 0; k2 < 4; ++k2)
      vb[dt][k2] = *(const sh8*)&vt[dt * 16 + (lane & 15)][k2 * 32 + kq];

  const float scale = 0.17677669529663687f;
  f32x4 zc = {};
  int rband = (lane >> 4) * 4;
  for (int it = 0; it < 7; ++it) {
    // Q fragment for this band
    int rq = it * 16 + (lane & 15);
    sh8 qf = *(const sh8*)&qkv[base + (size_t)rq * 768 + h * 32 + kq];
    f32x4 s[7];
#pragma unroll
    for (int jt = 0; jt < 7; ++jt)
      s[jt] = __builtin_amdgcn_mfma_f32_16x16x32_bf16(qf, kf[jt], zc, 0, 0, 0);
    // softmax (unnormalized exp; scores small)
    float p[7][4], linv[4];
#pragma unroll
    for (int j = 0; j < 4; ++j) {
      int r2 = it * 16 + rband + j;
      float rs = 0.f;
#pragma unroll
      for (int jt = 0; jt < 7; ++jt) {
        int c = jt * 16 + (lane & 15);
        float v = s[jt][j] * scale + bt[r2 * 112 + c];
        float e = __expf(v);
        if (jt == 6 && (lane & 15) >= 2) e = 0.f;   // cols >= 98
        p[jt][j] = e;
        rs += e;
      }
      rs += __shfl_xor(rs, 1, 64); rs += __shfl_xor(rs, 2, 64);
      rs += __shfl_xor(rs, 4, 64); rs += __shfl_xor(rs, 8, 64);
      linv[j] = 1.f / rs;
    }
    // write normalized P (bf16) to LDS band
#pragma unroll
    for (int j = 0; j < 4; ++j)
#pragma unroll
      for (int jt = 0; jt < 7; ++jt) {
        bf16 bv = __float2bfloat16(p[jt][j] * linv[j]);
        pb[rband + j][jt * 16 + (lane & 15)] = *(short*)&bv;
      }
    __syncthreads();
    // PV: O_band = P_band · V   (A=P rows, B=V^T rows)
    sh8 pa[4];
#pragma unroll
    for (int k2 = 0; k2 < 4; ++k2)
      pa[k2] = *(const sh8*)&pb[lane & 15][k2 * 32 + kq];
    f32x4 o[2] = {};
#pragma unroll
    for (int dt = 0; dt < 2; ++dt)
#pragma unroll
      for (int k2 = 0; k2 < 4; ++k2)
        o[dt] = __builtin_amdgcn_mfma_f32_16x16x32_bf16(pa[k2], vb[dt][k2], o[dt], 0, 0, 0);
#pragma unroll
    for (int j = 0; j < 4; ++j) {
      int r2 = it * 16 + rband + j;
      if (r2 < 98) {
#pragma unroll
        for (int dt = 0; dt < 2; ++dt) {
          bf16 ov = __float2bfloat16(o[dt][j]);
          aout[((size_t)wl * 98 + r2) * 256 + h * 32 + dt * 16 + (lane & 15)] = ov;
        }
      }
    }
    __syncthreads();
  }
}

// ---------------- residual + LN2: linear streaming ----------------
__global__ __launch_bounds__(256) void k_xres_ln2_lin(
    const float* __restrict__ xtw, const bf16* __restrict__ pout,
    const float* __restrict__ g, const float* __restrict__ bb,
    float* __restrict__ xres, bf16* __restrict__ ln2) {
  int rl = blockIdx.x * 4 + (threadIdx.x >> 6);
  int lane = threadIdx.x & 63;
  int c0 = lane * 4;
  float4 v = *(const float4*)(xtw + (size_t)rl * 256 + c0);
  ushort4 pu = *(const ushort4*)(pout + (size_t)rl * 256 + c0);
  v.x += __bfloat162float(*(bf16*)&pu.x);
  v.y += __bfloat162float(*(bf16*)&pu.y);
  v.z += __bfloat162float(*(bf16*)&pu.z);
  v.w += __bfloat162float(*(bf16*)&pu.w);
  *(float4*)(xres + (size_t)rl * 256 + c0) = v;
  float s = v.x + v.y + v.z + v.w;
  float s2 = v.x * v.x + v.y * v.y + v.z * v.z + v.w * v.w;
#pragma unroll
  for (int off = 32; off; off >>= 1) { s += __shfl_xor(s, off, 64); s2 += __shfl_xor(s2, off, 64); }
  float mu = s * (1.f / 256.f);
  float var = s2 * (1.f / 256.f) - mu * mu;
  float rs = rsqrtf(var + 1e-5f);
  float4 gg = *(const float4*)(g + c0);
  float4 bv = *(const float4*)(bb + c0);
  bf16 tmp[4];
  tmp[0] = __float2bfloat16((v.x - mu) * rs * gg.x + bv.x);
  tmp[1] = __float2bfloat16((v.y - mu) * rs * gg.y + bv.y);
  tmp[2] = __float2bfloat16((v.z - mu) * rs * gg.z + bv.z);
  tmp[3] = __float2bfloat16((v.w - mu) * rs * gg.w + bv.w);
  *(ushort4*)(&ln2[(size_t)rl * 256 + c0]) = *(ushort4*)tmp;
}

// ---------------- final: chunk-local y (f32 windowed) -> (B,D,C,W,H) ----------------
__global__ __launch_bounds__(256) void k_final_c(const float* __restrict__ y,
                                                 float* __restrict__ out, int cchunk) {
  int t = blockIdx.x;              // 672 = 84w * 4i * 2b
  int w0 = t % 84;
  int t2 = t / 84;
  int i = t2 & 3, b = t2 >> 2;
  int d0 = (cchunk * 4 + 1 + i) & 7;
  __shared__ float tile[84][65];
  __shared__ int rtab[84];
  int tid = threadIdx.x;
  if (tid < 84) rtab[tid] = inv_row(b, d0, w0, tid);
  __syncthreads();
  for (int c0 = 0; c0 < 256; c0 += 64) {
    for (int idx = tid; idx < 84 * 64; idx += 256) {
      int hh = idx >> 6, cc = idx & 63;
      tile[hh][cc] = y[(size_t)rtab[hh] * 256 + c0 + cc];
    }
    __syncthreads();
    for (int idx = tid; idx < 64 * 84; idx += 256) {
      int cc = idx / 84, hh = idx - cc * 84;
      out[((((size_t)b * 8 + d0) * 256 + c0 + cc) * 84 + w0) * 84 + hh] = tile[hh][cc];
    }
    __syncthreads();
  }
}

// ---------------- launch ----------------
extern "C" void kernel_launch(void* const* d_in, const int* in_sizes, int n_in,
                              void* d_out, int out_size, void* d_ws, size_t ws_size,
                              hipStream_t stream) {
  const float* x      = (const float*)d_in[0];
  const float* n1g    = (const float*)d_in[1];
  const float* n1b    = (const float*)d_in[2];
  const float* qkv_w  = (const float*)d_in[3];
  const float* rpb    = (const float*)d_in[4];
  const float* proj_w = (const float*)d_in[5];
  const float* proj_b = (const float*)d_in[6];
  const float* n2g    = (const float*)d_in[7];
  const float* n2b    = (const float*)d_in[8];
  const float* fc1_w  = (const float*)d_in[9];
  const float* fc1_b  = (const float*)d_in[10];
  const float* fc2_w  = (const float*)d_in[11];
  const float* fc2_b  = (const float*)d_in[12];
  float* out = (float*)d_out;

  // ---- persistent: weights + bias table ----
  char* w = (char*)d_ws;
  size_t off = 0;
  bf16* wq = (bf16*)(w + off); off += (size_t)768 * 256 * 2;
  bf16* wp = (bf16*)(w + off); off += (size_t)256 * 256 * 2;
  bf16* w1 = (bf16*)(w + off); off += (size_t)1024 * 256 * 2;
  bf16* w2 = (bf16*)(w + off); off += (size_t)1024 * 256 * 2;
  float* tbl = (float*)(w + off); off += (size_t)8 * 8 * 112 * 112 * 4;  // 3.2 MB

  // ---- per-chunk buffers (~274 MB total; known-good budget ~290 MB) ----
  float* xtw  = (float*)(w + off); off += (size_t)M2 * 1024;    // 57.8 MB (also y)
  bf16*  xw   = (bf16*)(w + off);  off += (size_t)M2 * 512;     // 28.9 MB (also aout)
  char*  qreg = w + off;           off += (size_t)M2 * 1536;    // 86.7 MB
  float* xres = (float*)(w + off); off += (size_t)M2 * 1024;    // 57.8 MB
  bf16*  hid  = (bf16*)(w + off);                               // sub-chunk sized
  bf16* qkvb = (bf16*)qreg;
  bf16* aout = xw;
  bf16* pout = (bf16*)qreg;
  bf16* ln2b = (bf16*)(qreg + (size_t)M2 * 512);
  float* ybuf = xtw;

  // MLP sub-chunk tiers: 147/49/21 row-tiles
  int subTiles = 21;
  if (off + (size_t)147 * 128 * 2048 + 1024 <= ws_size) subTiles = 147;
  else if (off + (size_t)49 * 128 * 2048 + 1024 <= ws_size) subTiles = 49;
  const int nsub = 441 / subTiles;
  const int MSUB = subTiles * 128;

  // weights -> bf16, bias table
  k_f2b<<<(196608 + 255) / 256, 256, 0, stream>>>(qkv_w, wq, 196608);
  k_f2b<<<(65536 + 255) / 256, 256, 0, stream>>>(proj_w, wp, 65536);
  k_f2b<<<(262144 + 255) / 256, 256, 0, stream>>>(fc1_w, w1, 262144);
  k_f2b<<<(262144 + 255) / 256, 256, 0, stream>>>(fc2_w, w2, 262144);
  k_bias<<<64, 256, 0, stream>>>(rpb, tbl);

  for (int c = 0; c < 2; ++c) {
    k_xpose_w<<<1344, 256, 0, stream>>>(x, xtw, c);
    k_ln1_lin<<<M2 / 4, 256, 0, stream>>>(xtw, n1g, n1b, xw);
    k_gemm_bt<0><<<441 * 6, 256, 0, stream>>>(xw, wq, M2, 768, 256, nullptr, nullptr, qkvb);
    k_attn_mfma<<<NWC * NH, 64, 0, stream>>>(qkvb, tbl, aout, 2 * c);
    k_gemm_bt<0><<<441 * 2, 256, 0, stream>>>(aout, wp, M2, 256, 256, proj_b, nullptr, pout);
    k_xres_ln2_lin<<<M2 / 4, 256, 0, stream>>>(xtw, pout, n2g, n2b, xres, ln2b);
    for (int s = 0; s < nsub; ++s) {
      size_t m0 = (size_t)s * MSUB;
      k_gemm_bt<1><<<subTiles * 8, 256, 0, stream>>>(
          ln2b + m0 * 256, w1, MSUB, 1024, 256, fc1_b, nullptr, hid);
      k_gemm_bt<2><<<subTiles * 2, 256, 0, stream>>>(
          hid, w2, MSUB, 256, 1024, fc2_b, xres + m0 * 256, ybuf + m0 * 256);
    }
    k_final_c<<<672, 256, 0, stream>>>(ybuf, out, c);
  }
}